// Round 8
// baseline (501.389 us; speedup 1.0000x reference)
//
#include <hip/hip_runtime.h>
#include <cstdint>

typedef short short8 __attribute__((ext_vector_type(8)));
typedef float f32x4 __attribute__((ext_vector_type(4)));

// fp32 -> bf16 (round-to-nearest-even), two packed into a u32
__device__ inline unsigned bfpack(float a, float b) {
    union { float f; unsigned u; } ua, ub;
    ua.f = a; ub.f = b;
    unsigned lo = (ua.u + 0x7FFFu + ((ua.u >> 16) & 1u)) >> 16;
    unsigned hi = (ub.u + 0x7FFFu + ((ub.u >> 16) & 1u)) & 0xFFFF0000u;
    return lo | hi;
}
__device__ inline unsigned short bf16of(float a) { return (unsigned short)bfpack(a, 0.0f); }
__device__ inline float bf2f(unsigned short s) {
    union { unsigned u; float f; } x; x.u = (unsigned)s << 16; return x.f;
}

// ------------- prepass: convert + transpose W[512][N] -> WT[N][512] bf16 ----
template <int N>
__global__ __launch_bounds__(256)
void cvt_w(const float* __restrict__ W, unsigned short* __restrict__ WT)
{
    const int g = blockIdx.x * 256 + threadIdx.x;
    if (g >= N * 64) return;
    const int n = g % N, d8 = g / N;
    const float* p = W + (size_t)d8 * 8 * N + n;
    uint4 u;
    u.x = bfpack(p[0],             p[(size_t)N]);
    u.y = bfpack(p[2 * (size_t)N], p[3 * (size_t)N]);
    u.z = bfpack(p[4 * (size_t)N], p[5 * (size_t)N]);
    u.w = bfpack(p[6 * (size_t)N], p[7 * (size_t)N]);
    *(uint4*)(WT + (size_t)n * 512 + d8 * 8) = u;
}

// ---------------- barrier-free streaming GEMM + closed-form scatter ---------
// Block owns 64 M-rows. A (64x512 bf16, 64 KB) resident in LDS for the whole
// block, filled ONCE from fp32 X (f=1 A reads; no cvt_x prepass). Then a
// barrier-free nt-loop over 256-wide N strips: B read global->VGPR (L2/L3-
// resident WT), A via swizzled ds_read_b128 (2-way residual = free). 8 waves
// (2M x 4N, wave tile 32x64). Memory pipe is never drained: no syncs, no
// vmcnt(0), no lockstep.
template <int MODE>
__global__ __launch_bounds__(512, 4)
void gemm_stream(const float* __restrict__ X,
                 const unsigned short* __restrict__ WT,
                 const float* __restrict__ BIAS, float* __restrict__ Y,
                 const unsigned short* __restrict__ EXTI,
                 unsigned short* __restrict__ EXTO)
{
    constexpr int K_L  = (MODE == 0) ? 64 : (MODE == 1) ? 128 : 256;
    constexpr int LOGK = (MODE == 0) ? 6  : (MODE == 1) ? 7   : 8;
    constexpr int N    = (MODE == 0) ? 1180 : (MODE == 1) ? 2881 : 1153;
    constexpr int XOFF = (MODE == 0) ? 0 : (MODE == 1) ? 64 : 192;
    constexpr int NT   = (N + 255) / 256;

    __shared__ __align__(16) unsigned short lA[64 * 512];   // 64 KB

    const int t    = threadIdx.x;            // 0..511
    const int lane = t & 63;
    const int wv   = t >> 6;                 // 0..7
    const int wr   = wv >> 2;                // M-half 0..1
    const int wc   = wv & 3;                 // N-quarter 0..3
    const int kq   = lane >> 4;              // 0..3
    const int lr16 = lane & 15;
    const int m0   = blockIdx.x * 64;

    // ---- one-time A fill: fp32 X -> bf16 -> swizzled LDS ------------------
    // per i: each wave covers one row (64 x 16B slots), 2KB coalesced reads.
    #pragma unroll
    for (int i = 0; i < 8; ++i) {
        const int idx = i * 512 + t;         // 0..4095
        const int row = idx >> 6;            // 0..63
        const int s   = idx & 63;            // 16B slot in row
        const int m   = m0 + row;
        const int b   = m >> LOGK, kd = m & (K_L - 1);
        const float* p = X + ((size_t)(b * 448 + XOFF + kd) << 9) + s * 8;
        const float4 v0 = *(const float4*)p;
        const float4 v1 = *(const float4*)(p + 4);
        uint4 u;
        u.x = bfpack(v0.x, v0.y); u.y = bfpack(v0.z, v0.w);
        u.z = bfpack(v1.x, v1.y); u.w = bfpack(v1.z, v1.w);
        *(uint4*)(&lA[row * 512 + ((s ^ (row & 7)) * 8)]) = u;
    }
    __syncthreads();   // the ONLY barrier in the kernel

    // ---- stream N in 256-wide strips --------------------------------------
    for (int nt = 0; nt < NT; ++nt) {
        const int n0 = nt * 256;

        const unsigned short* bp[4];
        #pragma unroll
        for (int ni = 0; ni < 4; ++ni) {
            int gc = n0 + wc * 64 + ni * 16 + lr16;
            if (gc > N - 1) gc = N - 1;      // N-tail clamp (reads only)
            bp[ni] = WT + (size_t)gc * 512 + kq * 8;
        }

        f32x4 acc[2][4] = {};

        #pragma unroll 4
        for (int kk16 = 0; kk16 < 16; ++kk16) {
            short8 bf[4];
            #pragma unroll
            for (int ni = 0; ni < 4; ++ni)
                bf[ni] = *(const short8*)(bp[ni] + kk16 * 32);
            short8 af[2];
            #pragma unroll
            for (int mi = 0; mi < 2; ++mi) {
                const int row = wr * 32 + mi * 16 + lr16;
                const int s   = kk16 * 4 + kq;
                af[mi] = *(const short8*)(&lA[row * 512 + ((s ^ (row & 7)) * 8)]);
            }
            #pragma unroll
            for (int mi = 0; mi < 2; ++mi)
                #pragma unroll
                for (int ni = 0; ni < 4; ++ni)
                    acc[mi][ni] = __builtin_amdgcn_mfma_f32_16x16x32_bf16(
                        af[mi], bf[ni], acc[mi][ni], 0, 0, 0);
        }

        // ---- epilogue for this strip: bias + scatter (EXT fusion, R4) -----
        #pragma unroll
        for (int ni = 0; ni < 4; ++ni) {
            const int n = n0 + wc * 64 + ni * 16 + lr16;
            if (n >= N) continue;
            const float bias = BIAS[n];
            #pragma unroll
            for (int mi = 0; mi < 2; ++mi) {
                #pragma unroll
                for (int r = 0; r < 4; ++r) {
                    const int m  = m0 + wr * 32 + mi * 16 + kq * 4 + r;
                    const int b  = m >> LOGK;
                    const int kd = m & (K_L - 1);
                    const float v = acc[mi][ni][r] + bias;
                    float* yb = Y + (size_t)b * 370816;
                    if constexpr (MODE == 0) {
                        if (n < 27)       yb[kd * 27 + n] = v;
                        else if (n == 27) yb[1728 + kd]   = v;
                        else EXTO[((size_t)(b * 64 + kd)) * 1152 + (n - 28)] = bf16of(v);
                    } else if constexpr (MODE == 1) {
                        if (n < 576) {
                            const float e = bf2f(EXTI[((size_t)(b * 64 + n / 9)) * 1152 + kd * 9 + n % 9]);
                            yb[1792 + kd * 576 + n] = 0.5f * (v + e);
                        } else if (n == 576) yb[75520 + kd] = 0.5f * v;
                        else EXTO[((size_t)(b * 128 + kd)) * 2304 + (n - 577)] = bf16of(v);
                    } else {
                        if (n < 1152) {
                            const float e = bf2f(EXTI[((size_t)(b * 128 + n / 9)) * 2304 + kd * 9 + n % 9]);
                            yb[75648 + kd * 1152 + n] = v + e;
                        } else yb[370560 + kd] = v;
                    }
                }
            }
        }
    }
}

extern "C" void kernel_launch(void* const* d_in, const int* in_sizes, int n_in,
                              void* d_out, int out_size, void* d_ws, size_t ws_size,
                              hipStream_t stream)
{
    const float* x  = (const float*)d_in[0];
    const float* W0 = (const float*)d_in[1];
    const float* b0 = (const float*)d_in[2];
    const float* W1 = (const float*)d_in[3];
    const float* b1 = (const float*)d_in[4];
    const float* W2 = (const float*)d_in[5];
    const float* b2 = (const float*)d_in[6];
    float* y = (float*)d_out;

    // ws (bf16): WT0 | WT1 | WT2 | EXT0[128*64*1152] | EXT1[128*128*2304]  (~100 MB)
    unsigned short* WT0  = (unsigned short*)d_ws;
    unsigned short* WT1  = WT0  + (size_t)1180 * 512;
    unsigned short* WT2  = WT1  + (size_t)2881 * 512;
    unsigned short* EXT0 = WT2  + (size_t)1153 * 512;
    unsigned short* EXT1 = EXT0 + (size_t)128 * 64 * 1152;

    cvt_w<1180><<<dim3((1180 * 64 + 255) / 256), 256, 0, stream>>>(W0, WT0);
    cvt_w<2881><<<dim3((2881 * 64 + 255) / 256), 256, 0, stream>>>(W1, WT1);
    cvt_w<1153><<<dim3((1153 * 64 + 255) / 256), 256, 0, stream>>>(W2, WT2);

    // grids: M/64 blocks; stream order carries the EXT dependency
    gemm_stream<0><<<dim3(128), 512, 0, stream>>>(x, WT0, b0, y, nullptr, EXT0);
    gemm_stream<1><<<dim3(256), 512, 0, stream>>>(x, WT1, b1, y, EXT0, EXT1);
    gemm_stream<2><<<dim3(512), 512, 0, stream>>>(x, WT2, b2, y, EXT1, nullptr);
}

// Round 9
// 413.247 us; speedup vs baseline: 1.2133x; 1.2133x over previous
//
#include <hip/hip_runtime.h>
#include <cstdint>

typedef short short8 __attribute__((ext_vector_type(8)));
typedef float f32x4 __attribute__((ext_vector_type(4)));

// fp32 -> bf16 (round-to-nearest-even), two packed into a u32
__device__ inline unsigned bfpack(float a, float b) {
    union { float f; unsigned u; } ua, ub;
    ua.f = a; ub.f = b;
    unsigned lo = (ua.u + 0x7FFFu + ((ua.u >> 16) & 1u)) >> 16;
    unsigned hi = (ub.u + 0x7FFFu + ((ub.u >> 16) & 1u)) & 0xFFFF0000u;
    return lo | hi;
}
__device__ inline unsigned short bf16of(float a) { return (unsigned short)bfpack(a, 0.0f); }
__device__ inline float bf2f(unsigned short s) {
    union { unsigned u; float f; } x; x.u = (unsigned)s << 16; return x.f;
}

// ---- prepass: W[512][N] -> fragment-packed WF ------------------------------
// frag (ntile,ktile) = 1024B: lane l holds n = ntile*16+(l&15),
// k = ktile*32+(l>>4)*8 .. +8. elem offset = (ntile*16+ktile)*512 + l*8.
// B-frag load in GEMM = one contiguous 1024B global_load_dwordx4 per wave.
template <int N, int NTP>
__global__ __launch_bounds__(256)
void cvt_w_frag(const float* __restrict__ W, unsigned short* __restrict__ WF)
{
    const int tid = blockIdx.x * 256 + threadIdx.x;   // < NTP*1024, exact grid
    const int ntile = tid >> 10;
    const int r     = tid & 1023;
    const int ktile = r >> 6;
    const int lane  = r & 63;
    int n = ntile * 16 + (lane & 15); if (n > N - 1) n = N - 1;  // tail clamp
    const int k0 = ktile * 32 + (lane >> 4) * 8;
    const float* p = W + (size_t)k0 * N + n;
    uint4 u;
    u.x = bfpack(p[0],             p[(size_t)N]);
    u.y = bfpack(p[2 * (size_t)N], p[3 * (size_t)N]);
    u.z = bfpack(p[4 * (size_t)N], p[5 * (size_t)N]);
    u.w = bfpack(p[6 * (size_t)N], p[7 * (size_t)N]);
    *(uint4*)(WF + (size_t)tid * 8) = u;
}

// ---- GEMM: A in LDS (K-tiled dbuf, f=1 X reads), B global->VGPR frags ------
// Block 128m x 256n, 4 waves (2m x 2n), wave tile 64 x 128 (4mi x 8ni of
// 16x16x32), acc 128 VGPR. Per 32-k step: 4 ds_read_b128 (A) + 8 contiguous
// 1024B B-loads + 32 MFMA -> LDS traffic/FLOP is 4x lower than the 128x128
// both-operands-in-LDS structure (R4 was LDS-BW-bound at 13% MfmaUtil).
template <int MODE>
__global__ __launch_bounds__(256, 2)
void gemm_stream(const float* __restrict__ X,
                 const unsigned short* __restrict__ WF,
                 const float* __restrict__ BIAS, float* __restrict__ Y,
                 const unsigned short* __restrict__ EXTI,
                 unsigned short* __restrict__ EXTO)
{
    constexpr int K_L  = (MODE == 0) ? 64 : (MODE == 1) ? 128 : 256;
    constexpr int LOGK = (MODE == 0) ? 6  : (MODE == 1) ? 7   : 8;
    constexpr int N    = (MODE == 0) ? 1180 : (MODE == 1) ? 2881 : 1153;
    constexpr int XOFF = (MODE == 0) ? 0 : (MODE == 1) ? 64 : 192;
    constexpr int NT   = (N + 255) / 256;

    __shared__ __align__(16) unsigned short lA[2][128 * 64];   // 32 KB

    const int t    = threadIdx.x;            // 0..255
    const int lane = t & 63;
    const int wv   = t >> 6;                 // 0..3
    const int wr   = wv >> 1;                // m half
    const int wcn  = wv & 1;                 // n half
    const int kq   = lane >> 4;
    const int lr16 = lane & 15;

    // bijective XCD-chunk swizzle (grids divisible by 8); N-minor order
    const int cpx = (int)gridDim.x >> 3;
    const int wg  = (blockIdx.x & 7) * cpx + (blockIdx.x >> 3);
    const int nt  = wg % NT;
    const int mt  = wg / NT;
    const int m0  = mt * 128;
    const int n0  = nt * 256;

    // B fragment pointers (8 per wave), lane offset folded in
    const unsigned short* wfp[8];
    #pragma unroll
    for (int ni = 0; ni < 8; ++ni) {
        const int ntile_g = (n0 >> 4) + wcn * 8 + ni;
        wfp[ni] = WF + (size_t)ntile_g * 16 * 512 + lane * 8;
    }

    f32x4 acc[4][8] = {};
    float4 av[4][2];   // in-flight A K-tile (fp32)

    auto loadA = [&](int kt) {               // issue early (T14)
        #pragma unroll
        for (int i = 0; i < 4; ++i) {
            const int idx = i * 256 + t;     // 1024 slots: row(0..127) x s(0..7)
            const int row = idx >> 3;
            const int s   = idx & 7;
            const int m   = m0 + row;
            const int b   = m >> LOGK, kd = m & (K_L - 1);
            const float* p = X + ((size_t)(b * 448 + XOFF + kd) << 9) + kt * 64 + s * 8;
            av[i][0] = *(const float4*)p;
            av[i][1] = *(const float4*)(p + 4);
        }
    };
    auto writeA = [&](int buf) {             // cvt + swizzled ds_write
        #pragma unroll
        for (int i = 0; i < 4; ++i) {
            const int idx = i * 256 + t;
            const int row = idx >> 3;
            const int s   = idx & 7;
            uint4 u;
            u.x = bfpack(av[i][0].x, av[i][0].y);
            u.y = bfpack(av[i][0].z, av[i][0].w);
            u.z = bfpack(av[i][1].x, av[i][1].y);
            u.w = bfpack(av[i][1].z, av[i][1].w);
            *(uint4*)(&lA[buf][row * 64 + ((s ^ (row & 7)) * 8)]) = u;
        }
    };

    // ---- prologue --------------------------------------------------------
    loadA(0); writeA(0);
    __syncthreads();

    // ---- K loop: 8 tiles of 64 -------------------------------------------
    #pragma unroll 1
    for (int kt = 0; kt < 8; ++kt) {
        const int buf = kt & 1;
        if (kt < 7) loadA(kt + 1);

        #pragma unroll
        for (int ks = 0; ks < 2; ++ks) {
            short8 af[4], bfr[8];
            #pragma unroll
            for (int mi = 0; mi < 4; ++mi) {
                const int row = wr * 64 + mi * 16 + lr16;
                const int s   = ks * 4 + kq;
                af[mi] = *(const short8*)(&lA[buf][row * 64 + ((s ^ (row & 7)) * 8)]);
            }
            #pragma unroll
            for (int ni = 0; ni < 8; ++ni)
                bfr[ni] = *(const short8*)(wfp[ni] + (kt * 2 + ks) * 512);
            #pragma unroll
            for (int mi = 0; mi < 4; ++mi)
                #pragma unroll
                for (int ni = 0; ni < 8; ++ni)
                    acc[mi][ni] = __builtin_amdgcn_mfma_f32_16x16x32_bf16(
                        af[mi], bfr[ni], acc[mi][ni], 0, 0, 0);
        }

        if (kt < 7) writeA(buf ^ 1);
        __syncthreads();
    }

    // ---- epilogue: bias + closed-form scatter (EXT fusion, verified R4) ---
    #pragma unroll
    for (int ni = 0; ni < 8; ++ni) {
        const int n = n0 + wcn * 128 + ni * 16 + lr16;
        if (n >= N) continue;
        const float bias = BIAS[n];
        #pragma unroll
        for (int mi = 0; mi < 4; ++mi) {
            #pragma unroll
            for (int r = 0; r < 4; ++r) {
                const int m  = m0 + wr * 64 + mi * 16 + kq * 4 + r;
                const int b  = m >> LOGK;
                const int kd = m & (K_L - 1);
                const float v = acc[mi][ni][r] + bias;
                float* yb = Y + (size_t)b * 370816;
                if constexpr (MODE == 0) {
                    if (n < 27)       yb[kd * 27 + n] = v;
                    else if (n == 27) yb[1728 + kd]   = v;
                    else EXTO[((size_t)(b * 64 + kd)) * 1152 + (n - 28)] = bf16of(v);
                } else if constexpr (MODE == 1) {
                    if (n < 576) {
                        const float e = bf2f(EXTI[((size_t)(b * 64 + n / 9)) * 1152 + kd * 9 + n % 9]);
                        yb[1792 + kd * 576 + n] = 0.5f * (v + e);
                    } else if (n == 576) yb[75520 + kd] = 0.5f * v;
                    else EXTO[((size_t)(b * 128 + kd)) * 2304 + (n - 577)] = bf16of(v);
                } else {
                    if (n < 1152) {
                        const float e = bf2f(EXTI[((size_t)(b * 128 + n / 9)) * 2304 + kd * 9 + n % 9]);
                        yb[75648 + kd * 1152 + n] = v + e;
                    } else yb[370560 + kd] = v;
                }
            }
        }
    }
}

extern "C" void kernel_launch(void* const* d_in, const int* in_sizes, int n_in,
                              void* d_out, int out_size, void* d_ws, size_t ws_size,
                              hipStream_t stream)
{
    const float* x  = (const float*)d_in[0];
    const float* W0 = (const float*)d_in[1];
    const float* b0 = (const float*)d_in[2];
    const float* W1 = (const float*)d_in[3];
    const float* b1 = (const float*)d_in[4];
    const float* W2 = (const float*)d_in[5];
    const float* b2 = (const float*)d_in[6];
    float* y = (float*)d_out;

    // padded n-tile counts (16-wide tiles covering NT*256 columns)
    constexpr int NTP0 = 5 * 16, NTP1 = 12 * 16, NTP2 = 5 * 16;

    // ws (bf16): WF0 | WF1 | WF2 | EXT0[128*64*1152] | EXT1[128*128*2304]  (~101 MB)
    unsigned short* WF0  = (unsigned short*)d_ws;
    unsigned short* WF1  = WF0  + (size_t)NTP0 * 16 * 512;
    unsigned short* WF2  = WF1  + (size_t)NTP1 * 16 * 512;
    unsigned short* EXT0 = WF2  + (size_t)NTP2 * 16 * 512;
    unsigned short* EXT1 = EXT0 + (size_t)128 * 64 * 1152;

    cvt_w_frag<1180, NTP0><<<dim3(NTP0 * 4), 256, 0, stream>>>(W0, WF0);
    cvt_w_frag<2881, NTP1><<<dim3(NTP1 * 4), 256, 0, stream>>>(W1, WF1);
    cvt_w_frag<1153, NTP2><<<dim3(NTP2 * 4), 256, 0, stream>>>(W2, WF2);

    // grids: (M/128) * NT; stream order carries the EXT dependency
    gemm_stream<0><<<dim3(64 * 5),   256, 0, stream>>>(x, WF0, b0, y, nullptr, EXT0);
    gemm_stream<1><<<dim3(128 * 12), 256, 0, stream>>>(x, WF1, b1, y, EXT0, EXT1);
    gemm_stream<2><<<dim3(256 * 5),  256, 0, stream>>>(x, WF2, b2, y, EXT1, nullptr);
}

// Round 10
// 321.793 us; speedup vs baseline: 1.5581x; 1.2842x over previous
//
#include <hip/hip_runtime.h>
#include <cstdint>

typedef short short8 __attribute__((ext_vector_type(8)));
typedef float f32x4 __attribute__((ext_vector_type(4)));

#define LDS_AS3(p) ((__attribute__((address_space(3))) unsigned*)(p))
#define GLB_AS1(p) ((const __attribute__((address_space(1))) unsigned*)(p))

// fp32 -> bf16 (round-to-nearest-even), two packed into a u32
__device__ inline unsigned bfpack(float a, float b) {
    union { float f; unsigned u; } ua, ub;
    ua.f = a; ub.f = b;
    unsigned lo = (ua.u + 0x7FFFu + ((ua.u >> 16) & 1u)) >> 16;
    unsigned hi = (ub.u + 0x7FFFu + ((ub.u >> 16) & 1u)) & 0xFFFF0000u;
    return lo | hi;
}
__device__ inline unsigned short bf16of(float a) { return (unsigned short)bfpack(a, 0.0f); }
__device__ inline float bf2f(unsigned short s) {
    union { unsigned u; float f; } x; x.u = (unsigned)s << 16; return x.f;
}

// ---------------- prepass: convert X to bf16 (same [.,448,512] layout) ------
__global__ __launch_bounds__(256)
void cvt_x(const float* __restrict__ X, unsigned short* __restrict__ XB)
{
    const int g = blockIdx.x * 256 + threadIdx.x;
    const float4 v0 = *(const float4*)(X + (size_t)g * 8);
    const float4 v1 = *(const float4*)(X + (size_t)g * 8 + 4);
    uint4 u;
    u.x = bfpack(v0.x, v0.y); u.y = bfpack(v0.z, v0.w);
    u.z = bfpack(v1.x, v1.y); u.w = bfpack(v1.z, v1.w);
    *(uint4*)(XB + (size_t)g * 8) = u;
}

// ------------- prepass: convert + transpose W[512][N] -> WT[N][512] bf16 ----
template <int N>
__global__ __launch_bounds__(256)
void cvt_w(const float* __restrict__ W, unsigned short* __restrict__ WT)
{
    const int g = blockIdx.x * 256 + threadIdx.x;
    if (g >= N * 64) return;
    const int n = g % N, d8 = g / N;
    const float* p = W + (size_t)d8 * 8 * N + n;
    uint4 u;
    u.x = bfpack(p[0],             p[(size_t)N]);
    u.y = bfpack(p[2 * (size_t)N], p[3 * (size_t)N]);
    u.z = bfpack(p[4 * (size_t)N], p[5 * (size_t)N]);
    u.w = bfpack(p[6 * (size_t)N], p[7 * (size_t)N]);
    *(uint4*)(WT + (size_t)n * 512 + d8 * 8) = u;
}

// ------------- 256x128 GEMM, 3-buffer ring, 2-tiles-ahead staging -----------
// Diagnosis R1-R8: dur invariant to bytes -> latency-bound on global_load_lds
// from HBM (~900cy) waited on too soon. Here: stage tile kt+2 during tile kt,
// wait vmcnt(6) at tile entry -> issue-to-wait distance = 2 K-tiles (~1400cy).
// ONE raw s_barrier per K-tile (8 total). 8 waves (4M x 2N), wave tile 64x64.
// Ring safety: tile kt+2's buffer ((kt+2)%3 == (kt-1)%3) last read in tile
// kt-1, finished behind the tile-kt entry barrier. Per-wave vmcnt -> barrier
// ordering makes all waves' tile-kt loads LDS-visible before any read.
template <int MODE>
__global__ __launch_bounds__(512, 2)
void gemm_pipe(const unsigned short* __restrict__ XB,
               const unsigned short* __restrict__ WT,
               const float* __restrict__ BIAS, float* __restrict__ Y,
               const unsigned short* __restrict__ EXTI,
               unsigned short* __restrict__ EXTO)
{
    constexpr int K_L  = (MODE == 0) ? 64 : (MODE == 1) ? 128 : 256;
    constexpr int LOGK = (MODE == 0) ? 6  : (MODE == 1) ? 7   : 8;
    constexpr int N    = (MODE == 0) ? 1180 : (MODE == 1) ? 2881 : 1153;
    constexpr int XOFF = (MODE == 0) ? 0 : (MODE == 1) ? 64 : 192;
    constexpr int NT   = (N + 127) / 128;

    __shared__ __align__(16) unsigned short lA[3 * 256 * 64];   // 96 KB
    __shared__ __align__(16) unsigned short lB[3 * 128 * 64];   // 48 KB

    const int t    = threadIdx.x;            // 0..511
    const int lane = t & 63;
    const int wv   = t >> 6;                 // 0..7
    const int wr   = wv >> 1;                // m wave 0..3
    const int wn   = wv & 1;                 // n wave 0..1
    const int kq   = lane >> 4;              // 0..3
    const int lr16 = lane & 15;

    // bijective XCD-chunk swizzle (grids divisible by 8); N-minor order
    const int cpx = (int)gridDim.x >> 3;
    const int wg  = (blockIdx.x & 7) * cpx + (blockIdx.x >> 3);
    const int nt  = wg % NT;
    const int mt  = wg / NT;
    const int m0  = mt * 256;
    const int n0  = nt * 128;

    // stage helpers: physical chunk (row,p) holds logical k-slot p^(row&7);
    // linear LDS dest, swizzle on the GLOBAL source (rule #21).
    auto stageA = [&](int buf, int kt, int rnd) {   // 4 rounds per tile
        const int c   = rnd * 512 + t;              // 0..2047
        const int row = c >> 3, p = c & 7, l = p ^ (row & 7);
        const int m   = m0 + row;
        const int b   = m >> LOGK, kd = m & (K_L - 1);
        const unsigned short* gp =
            XB + ((size_t)(b * 448 + XOFF + kd) << 9) + kt * 64 + l * 8;
        __builtin_amdgcn_global_load_lds(GLB_AS1(gp),
            LDS_AS3(lA + (size_t)buf * (256 * 64) + c * 8), 16, 0, 0);
    };
    auto stageB = [&](int buf, int kt, int rnd) {   // 2 rounds per tile
        const int c   = rnd * 512 + t;              // 0..1023
        const int row = c >> 3, p = c & 7, l = p ^ (row & 7);
        int gc = n0 + row; if (gc > N - 1) gc = N - 1;   // N-tail clamp
        const unsigned short* gp = WT + (size_t)gc * 512 + kt * 64 + l * 8;
        __builtin_amdgcn_global_load_lds(GLB_AS1(gp),
            LDS_AS3(lB + (size_t)buf * (128 * 64) + c * 8), 16, 0, 0);
    };
    auto stage3 = [&](int buf, int kt, int half) {  // 3 loads/thread
        stageA(buf, kt, half * 2);
        stageA(buf, kt, half * 2 + 1);
        stageB(buf, kt, half);
    };

    f32x4 acc[4][4] = {};

    // ---- prologue: tiles 0 and 1 fully issued (12 loads/thread) -----------
    stage3(0, 0, 0); stage3(0, 0, 1);
    stage3(1, 1, 0); stage3(1, 1, 1);

    // ---- K loop: 8 tiles of 64; one vmcnt + one barrier per tile ----------
    #pragma unroll 1
    for (int kt = 0; kt < 8; ++kt) {
        const int buf = kt % 3;
        // retire tile kt (issued 2 tiles ago); keep tile kt+1's 6 in flight
        if (kt < 7) asm volatile("s_waitcnt vmcnt(6)" ::: "memory");
        else        asm volatile("s_waitcnt vmcnt(0)" ::: "memory");
        __builtin_amdgcn_s_barrier();

        const unsigned short* Ab = lA + (size_t)buf * (256 * 64);
        const unsigned short* Bb = lB + (size_t)buf * (128 * 64);

        #pragma unroll
        for (int ks = 0; ks < 2; ++ks) {
            const int s = ks * 4 + kq;
            short8 af[4], bf[4];
            #pragma unroll
            for (int mi = 0; mi < 4; ++mi) {
                const int row = wr * 64 + mi * 16 + lr16;
                af[mi] = *(const short8*)(Ab + row * 64 + ((s ^ (row & 7)) * 8));
            }
            #pragma unroll
            for (int ni = 0; ni < 4; ++ni) {
                const int row = wn * 64 + ni * 16 + lr16;
                bf[ni] = *(const short8*)(Bb + row * 64 + ((s ^ (row & 7)) * 8));
            }
            if (kt < 6) stage3((kt + 2) % 3, kt + 2, ks);   // 2-ahead prefetch
            __builtin_amdgcn_s_setprio(1);
            #pragma unroll
            for (int mi = 0; mi < 4; ++mi)
                #pragma unroll
                for (int ni = 0; ni < 4; ++ni)
                    acc[mi][ni] = __builtin_amdgcn_mfma_f32_16x16x32_bf16(
                        af[mi], bf[ni], acc[mi][ni], 0, 0, 0);
            __builtin_amdgcn_s_setprio(0);
        }
    }

    // ---- epilogue: bias + closed-form scatter (EXT fusion, verified R4) ---
    #pragma unroll
    for (int ni = 0; ni < 4; ++ni) {
        const int n = n0 + wn * 64 + ni * 16 + lr16;
        if (n >= N) continue;
        const float bias = BIAS[n];
        #pragma unroll
        for (int mi = 0; mi < 4; ++mi) {
            #pragma unroll
            for (int r = 0; r < 4; ++r) {
                const int m  = m0 + wr * 64 + mi * 16 + kq * 4 + r;
                const int b  = m >> LOGK;
                const int kd = m & (K_L - 1);
                const float v = acc[mi][ni][r] + bias;
                float* yb = Y + (size_t)b * 370816;
                if constexpr (MODE == 0) {
                    if (n < 27)       yb[kd * 27 + n] = v;
                    else if (n == 27) yb[1728 + kd]   = v;
                    else EXTO[((size_t)(b * 64 + kd)) * 1152 + (n - 28)] = bf16of(v);
                } else if constexpr (MODE == 1) {
                    if (n < 576) {
                        const float e = bf2f(EXTI[((size_t)(b * 64 + n / 9)) * 1152 + kd * 9 + n % 9]);
                        yb[1792 + kd * 576 + n] = 0.5f * (v + e);
                    } else if (n == 576) yb[75520 + kd] = 0.5f * v;
                    else EXTO[((size_t)(b * 128 + kd)) * 2304 + (n - 577)] = bf16of(v);
                } else {
                    if (n < 1152) {
                        const float e = bf2f(EXTI[((size_t)(b * 128 + n / 9)) * 2304 + kd * 9 + n % 9]);
                        yb[75648 + kd * 1152 + n] = v + e;
                    } else yb[370560 + kd] = v;
                }
            }
        }
    }
}

extern "C" void kernel_launch(void* const* d_in, const int* in_sizes, int n_in,
                              void* d_out, int out_size, void* d_ws, size_t ws_size,
                              hipStream_t stream)
{
    const float* x  = (const float*)d_in[0];
    const float* W0 = (const float*)d_in[1];
    const float* b0 = (const float*)d_in[2];
    const float* W1 = (const float*)d_in[3];
    const float* b1 = (const float*)d_in[4];
    const float* W2 = (const float*)d_in[5];
    const float* b2 = (const float*)d_in[6];
    float* y = (float*)d_out;

    // ws (bf16): XB[128*448*512] | WT0 | WT1 | WT2 | EXT0[128*64*1152] | EXT1[128*128*2304]
    unsigned short* XB   = (unsigned short*)d_ws;
    unsigned short* WT0  = XB   + (size_t)128 * 448 * 512;
    unsigned short* WT1  = WT0  + (size_t)1180 * 512;
    unsigned short* WT2  = WT1  + (size_t)2881 * 512;
    unsigned short* EXT0 = WT2  + (size_t)1153 * 512;
    unsigned short* EXT1 = EXT0 + (size_t)128 * 64 * 1152;

    cvt_x<<<dim3(14336), 256, 0, stream>>>(x, XB);
    cvt_w<1180><<<dim3((1180 * 64 + 255) / 256), 256, 0, stream>>>(W0, WT0);
    cvt_w<2881><<<dim3((2881 * 64 + 255) / 256), 256, 0, stream>>>(W1, WT1);
    cvt_w<1153><<<dim3((1153 * 64 + 255) / 256), 256, 0, stream>>>(W2, WT2);

    // grids: (M/256) * ceil(N/128); all divisible by 8; stream order = EXT dep
    gemm_pipe<0><<<dim3(32 * 10),  512, 0, stream>>>(XB, WT0, b0, y, nullptr, EXT0);
    gemm_pipe<1><<<dim3(64 * 23),  512, 0, stream>>>(XB, WT1, b1, y, EXT0, EXT1);
    gemm_pipe<2><<<dim3(128 * 10), 512, 0, stream>>>(XB, WT2, b2, y, EXT1, nullptr);
}

// Round 11
// 308.208 us; speedup vs baseline: 1.6268x; 1.0441x over previous
//
#include <hip/hip_runtime.h>
#include <cstdint>

typedef short short8 __attribute__((ext_vector_type(8)));
typedef float f32x4 __attribute__((ext_vector_type(4)));

#define LDS_AS3(p) ((__attribute__((address_space(3))) unsigned*)(p))
#define GLB_AS1(p) ((const __attribute__((address_space(1))) unsigned*)(p))

// fp32 -> bf16 (round-to-nearest-even), two packed into a u32
__device__ inline unsigned bfpack(float a, float b) {
    union { float f; unsigned u; } ua, ub;
    ua.f = a; ub.f = b;
    unsigned lo = (ua.u + 0x7FFFu + ((ua.u >> 16) & 1u)) >> 16;
    unsigned hi = (ub.u + 0x7FFFu + ((ub.u >> 16) & 1u)) & 0xFFFF0000u;
    return lo | hi;
}
__device__ inline unsigned short bf16of(float a) { return (unsigned short)bfpack(a, 0.0f); }
__device__ inline float bf2f(unsigned short s) {
    union { unsigned u; float f; } x; x.u = (unsigned)s << 16; return x.f;
}

// ---------------- prepass: convert X to bf16 (same [.,448,512] layout) ------
__global__ __launch_bounds__(256)
void cvt_x(const float* __restrict__ X, unsigned short* __restrict__ XB)
{
    const int g = blockIdx.x * 256 + threadIdx.x;
    const float4 v0 = *(const float4*)(X + (size_t)g * 8);
    const float4 v1 = *(const float4*)(X + (size_t)g * 8 + 4);
    uint4 u;
    u.x = bfpack(v0.x, v0.y); u.y = bfpack(v0.z, v0.w);
    u.z = bfpack(v1.x, v1.y); u.w = bfpack(v1.z, v1.w);
    *(uint4*)(XB + (size_t)g * 8) = u;
}

// ------------- prepass: convert + transpose W[512][N] -> WT[N][512] bf16 ----
template <int N>
__global__ __launch_bounds__(256)
void cvt_w(const float* __restrict__ W, unsigned short* __restrict__ WT)
{
    const int g = blockIdx.x * 256 + threadIdx.x;
    if (g >= N * 64) return;
    const int n = g % N, d8 = g / N;
    const float* p = W + (size_t)d8 * 8 * N + n;
    uint4 u;
    u.x = bfpack(p[0],             p[(size_t)N]);
    u.y = bfpack(p[2 * (size_t)N], p[3 * (size_t)N]);
    u.z = bfpack(p[4 * (size_t)N], p[5 * (size_t)N]);
    u.w = bfpack(p[6 * (size_t)N], p[7 * (size_t)N]);
    *(uint4*)(WT + (size_t)n * 512 + d8 * 8) = u;
}

// ------- 256x256 GEMM, 1024 thr (16 waves, 4x4), BK=64 dbuf + scatter -------
// Mechanism (R3 vs R9 measurement): staging BW scales with waves/SIMD;
// time ~ staged_bytes / BW. This round: minimum staged bytes (256^2 tile,
// 393MB for L1) x maximum issue parallelism (4 waves/SIMD from ONE block).
// Per K-step compute (~2500cy/SIMD) >> HBM latency (900cy), so the simple
// stage(next)->compute(cur)->__syncthreads schedule hides the drain.
template <int MODE>
__global__ __launch_bounds__(1024, 4)
void gemm_big(const unsigned short* __restrict__ XB,
              const unsigned short* __restrict__ WT,
              const float* __restrict__ BIAS, float* __restrict__ Y,
              const unsigned short* __restrict__ EXTI,
              unsigned short* __restrict__ EXTO)
{
    constexpr int K_L  = (MODE == 0) ? 64 : (MODE == 1) ? 128 : 256;
    constexpr int LOGK = (MODE == 0) ? 6  : (MODE == 1) ? 7   : 8;
    constexpr int N    = (MODE == 0) ? 1180 : (MODE == 1) ? 2881 : 1153;
    constexpr int XOFF = (MODE == 0) ? 0 : (MODE == 1) ? 64 : 192;
    constexpr int NT   = (N + 255) / 256;

    __shared__ __align__(16) unsigned short lA[2][256 * 64];   // 64 KB
    __shared__ __align__(16) unsigned short lB[2][256 * 64];   // 64 KB

    const int t    = threadIdx.x;            // 0..1023
    const int lane = t & 63;
    const int wv   = t >> 6;                 // 0..15
    const int wr   = wv >> 2;                // m wave 0..3
    const int wc   = wv & 3;                 // n wave 0..3
    const int kq   = lane >> 4;              // 0..3
    const int lr16 = lane & 15;

    // bijective XCD-chunk swizzle (grids divisible by 8); N-minor order
    const int cpx = (int)gridDim.x >> 3;
    const int wg  = (blockIdx.x & 7) * cpx + (blockIdx.x >> 3);
    const int nt  = wg % NT;
    const int mt  = wg / NT;
    const int m0  = mt * 256;
    const int n0  = nt * 256;

    // stage one K-tile (256 rows x 64 k for A and B): 4 gload_lds/thread.
    // physical chunk (row,p) holds logical slot p^(row&7); linear LDS dest,
    // swizzle on the GLOBAL source (rule #21).
    auto stage = [&](int buf, int kt) {
        #pragma unroll
        for (int i = 0; i < 2; ++i) {
            const int c   = i * 1024 + t;            // 0..2047
            const int row = c >> 3, p = c & 7, l = p ^ (row & 7);
            const int m   = m0 + row;
            const int b   = m >> LOGK, kd = m & (K_L - 1);
            const unsigned short* gp =
                XB + ((size_t)(b * 448 + XOFF + kd) << 9) + kt * 64 + l * 8;
            __builtin_amdgcn_global_load_lds(GLB_AS1(gp),
                LDS_AS3(&lA[buf][c * 8]), 16, 0, 0);
        }
        #pragma unroll
        for (int i = 0; i < 2; ++i) {
            const int c   = i * 1024 + t;
            const int row = c >> 3, p = c & 7, l = p ^ (row & 7);
            int gc = n0 + row; if (gc > N - 1) gc = N - 1;   // N-tail clamp
            const unsigned short* gp = WT + (size_t)gc * 512 + kt * 64 + l * 8;
            __builtin_amdgcn_global_load_lds(GLB_AS1(gp),
                LDS_AS3(&lB[buf][c * 8]), 16, 0, 0);
        }
    };

    f32x4 acc[4][4] = {};

    // ---- prologue --------------------------------------------------------
    stage(0, 0);
    __syncthreads();

    // ---- K loop: 8 tiles of 64; stage(next) -> compute(cur) -> sync -------
    #pragma unroll 1
    for (int kt = 0; kt < 8; ++kt) {
        const int buf = kt & 1;
        if (kt < 7) stage(buf ^ 1, kt + 1);

        #pragma unroll
        for (int ks = 0; ks < 2; ++ks) {
            const int s = ks * 4 + kq;
            short8 af[4], bf[4];
            #pragma unroll
            for (int mi = 0; mi < 4; ++mi) {
                const int row = wr * 64 + mi * 16 + lr16;
                af[mi] = *(const short8*)(&lA[buf][row * 64 + ((s ^ (row & 7)) * 8)]);
            }
            #pragma unroll
            for (int ni = 0; ni < 4; ++ni) {
                const int row = wc * 64 + ni * 16 + lr16;
                bf[ni] = *(const short8*)(&lB[buf][row * 64 + ((s ^ (row & 7)) * 8)]);
            }
            __builtin_amdgcn_s_setprio(1);
            #pragma unroll
            for (int mi = 0; mi < 4; ++mi)
                #pragma unroll
                for (int ni = 0; ni < 4; ++ni)
                    acc[mi][ni] = __builtin_amdgcn_mfma_f32_16x16x32_bf16(
                        af[mi], bf[ni], acc[mi][ni], 0, 0, 0);
            __builtin_amdgcn_s_setprio(0);
        }
        __syncthreads();
    }

    // ---- epilogue: bias + closed-form scatter (EXT fusion, verified R4) ---
    #pragma unroll
    for (int ni = 0; ni < 4; ++ni) {
        const int n = n0 + wc * 64 + ni * 16 + lr16;
        if (n >= N) continue;
        const float bias = BIAS[n];
        #pragma unroll
        for (int mi = 0; mi < 4; ++mi) {
            #pragma unroll
            for (int r = 0; r < 4; ++r) {
                const int m  = m0 + wr * 64 + mi * 16 + kq * 4 + r;
                const int b  = m >> LOGK;
                const int kd = m & (K_L - 1);
                const float v = acc[mi][ni][r] + bias;
                float* yb = Y + (size_t)b * 370816;
                if constexpr (MODE == 0) {
                    if (n < 27)       yb[kd * 27 + n] = v;
                    else if (n == 27) yb[1728 + kd]   = v;
                    else EXTO[((size_t)(b * 64 + kd)) * 1152 + (n - 28)] = bf16of(v);
                } else if constexpr (MODE == 1) {
                    if (n < 576) {
                        const float e = bf2f(EXTI[((size_t)(b * 64 + n / 9)) * 1152 + kd * 9 + n % 9]);
                        yb[1792 + kd * 576 + n] = 0.5f * (v + e);
                    } else if (n == 576) yb[75520 + kd] = 0.5f * v;
                    else EXTO[((size_t)(b * 128 + kd)) * 2304 + (n - 577)] = bf16of(v);
                } else {
                    if (n < 1152) {
                        const float e = bf2f(EXTI[((size_t)(b * 128 + n / 9)) * 2304 + kd * 9 + n % 9]);
                        yb[75648 + kd * 1152 + n] = v + e;
                    } else yb[370560 + kd] = v;
                }
            }
        }
    }
}

extern "C" void kernel_launch(void* const* d_in, const int* in_sizes, int n_in,
                              void* d_out, int out_size, void* d_ws, size_t ws_size,
                              hipStream_t stream)
{
    const float* x  = (const float*)d_in[0];
    const float* W0 = (const float*)d_in[1];
    const float* b0 = (const float*)d_in[2];
    const float* W1 = (const float*)d_in[3];
    const float* b1 = (const float*)d_in[4];
    const float* W2 = (const float*)d_in[5];
    const float* b2 = (const float*)d_in[6];
    float* y = (float*)d_out;

    // ws (bf16): XB[128*448*512] | WT0 | WT1 | WT2 | EXT0[128*64*1152] | EXT1[128*128*2304]
    unsigned short* XB   = (unsigned short*)d_ws;
    unsigned short* WT0  = XB   + (size_t)128 * 448 * 512;
    unsigned short* WT1  = WT0  + (size_t)1180 * 512;
    unsigned short* WT2  = WT1  + (size_t)2881 * 512;
    unsigned short* EXT0 = WT2  + (size_t)1153 * 512;
    unsigned short* EXT1 = EXT0 + (size_t)128 * 64 * 1152;

    cvt_x<<<dim3(14336), 256, 0, stream>>>(x, XB);
    cvt_w<1180><<<dim3((1180 * 64 + 255) / 256), 256, 0, stream>>>(W0, WT0);
    cvt_w<2881><<<dim3((2881 * 64 + 255) / 256), 256, 0, stream>>>(W1, WT1);
    cvt_w<1153><<<dim3((1153 * 64 + 255) / 256), 256, 0, stream>>>(W2, WT2);

    // grids: (M/256) * ceil(N/256); all divisible by 8; stream order = EXT dep
    gemm_big<0><<<dim3(32 * 5),   1024, 0, stream>>>(XB, WT0, b0, y, nullptr, EXT0);
    gemm_big<1><<<dim3(64 * 12),  1024, 0, stream>>>(XB, WT1, b1, y, EXT0, EXT1);
    gemm_big<2><<<dim3(128 * 5),  1024, 0, stream>>>(XB, WT2, b2, y, EXT1, nullptr);
}